// Round 1
// baseline (1757.168 us; speedup 1.0000x reference)
//
#include <hip/hip_runtime.h>

#define B_ 8
#define N_ 2048

// ---------------- per-cloud normalize (f64 mean/var, fp32 ops match ref) ----------------
__global__ __launch_bounds__(256) void normalize_kernel(const float* __restrict__ pos,
                                                        float* __restrict__ pnorm) {
  const int b = blockIdx.x, tid = threadIdx.x;
  const float* base = pos + (size_t)b * N_ * 3;
  float px[8], py[8], pz[8];
  double sx = 0.0, sy = 0.0, sz = 0.0;
#pragma unroll
  for (int k = 0; k < 8; ++k) {
    int g = tid * 8 + k;
    px[k] = base[g * 3 + 0];
    py[k] = base[g * 3 + 1];
    pz[k] = base[g * 3 + 2];
    sx += (double)px[k]; sy += (double)py[k]; sz += (double)pz[k];
  }
  __shared__ double wsum[3][4];
  __shared__ float bc[6];
  const int wid = tid >> 6, lid = tid & 63;
#pragma unroll
  for (int off = 32; off >= 1; off >>= 1) {
    sx += __shfl_down(sx, off);
    sy += __shfl_down(sy, off);
    sz += __shfl_down(sz, off);
  }
  if (lid == 0) { wsum[0][wid] = sx; wsum[1][wid] = sy; wsum[2][wid] = sz; }
  __syncthreads();
  if (tid == 0) {
    bc[0] = (float)((wsum[0][0] + wsum[0][1] + wsum[0][2] + wsum[0][3]) / 2048.0);
    bc[1] = (float)((wsum[1][0] + wsum[1][1] + wsum[1][2] + wsum[1][3]) / 2048.0);
    bc[2] = (float)((wsum[2][0] + wsum[2][1] + wsum[2][2] + wsum[2][3]) / 2048.0);
  }
  __syncthreads();
  const float mx = bc[0], my = bc[1], mz = bc[2];
  float dx[8], dy[8], dz[8];
  double qx = 0.0, qy = 0.0, qz = 0.0;
#pragma unroll
  for (int k = 0; k < 8; ++k) {
    dx[k] = __fsub_rn(px[k], mx);
    dy[k] = __fsub_rn(py[k], my);
    dz[k] = __fsub_rn(pz[k], mz);
    qx += (double)__fmul_rn(dx[k], dx[k]);
    qy += (double)__fmul_rn(dy[k], dy[k]);
    qz += (double)__fmul_rn(dz[k], dz[k]);
  }
#pragma unroll
  for (int off = 32; off >= 1; off >>= 1) {
    qx += __shfl_down(qx, off);
    qy += __shfl_down(qy, off);
    qz += __shfl_down(qz, off);
  }
  if (lid == 0) { wsum[0][wid] = qx; wsum[1][wid] = qy; wsum[2][wid] = qz; }
  __syncthreads();
  if (tid == 0) {
    bc[3] = __fadd_rn(__fsqrt_rn((float)((wsum[0][0]+wsum[0][1]+wsum[0][2]+wsum[0][3]) / 2047.0)), 1e-6f);
    bc[4] = __fadd_rn(__fsqrt_rn((float)((wsum[1][0]+wsum[1][1]+wsum[1][2]+wsum[1][3]) / 2047.0)), 1e-6f);
    bc[5] = __fadd_rn(__fsqrt_rn((float)((wsum[2][0]+wsum[2][1]+wsum[2][2]+wsum[2][3]) / 2047.0)), 1e-6f);
  }
  __syncthreads();
  const float isx = bc[3], isy = bc[4], isz = bc[5];
  float* ob = pnorm + (size_t)b * N_ * 3;
#pragma unroll
  for (int k = 0; k < 8; ++k) {
    int g = tid * 8 + k;
    ob[g * 3 + 0] = __fdiv_rn(dx[k], isx);
    ob[g * 3 + 1] = __fdiv_rn(dy[k], isy);
    ob[g * 3 + 2] = __fdiv_rn(dz[k], isz);
  }
}

// ---------------- farthest point sampling: one wave per cloud ----------------
// Bit-exact distance: ((dx*dx + dy*dy) + dz*dz) via _rn ops, min via fminf,
// argmax with first-index tie-break (matches jnp.argmax).
template <int NPL>
__global__ __launch_bounds__(64) void fps_kernel(const float* __restrict__ pts,
                                                 int k_out,
                                                 int* __restrict__ idx_out,
                                                 float* __restrict__ pos_out) {
  const int b = blockIdx.x;
  const int lane = threadIdx.x;
  const int n = NPL * 64;
  __shared__ float X[NPL * 64], Y[NPL * 64], Z[NPL * 64];
  float x[NPL], y[NPL], z[NPL], dist[NPL];
  const float* base = pts + (size_t)b * n * 3;
#pragma unroll
  for (int j = 0; j < NPL; ++j) {
    int g = lane * NPL + j;
    x[j] = base[g * 3 + 0];
    y[j] = base[g * 3 + 1];
    z[j] = base[g * 3 + 2];
    X[g] = x[j]; Y[g] = y[j]; Z[g] = z[j];
    dist[j] = 1e10f;
  }
  __syncthreads();
  int cur = 0;
  if (lane == 0) idx_out[b * k_out + 0] = 0;
  for (int t = 1; t < k_out; ++t) {
    const float qx = X[cur], qy = Y[cur], qz = Z[cur];
    if (lane == 0) {
      float* pp = pos_out + ((size_t)b * k_out + (t - 1)) * 3;
      pp[0] = qx; pp[1] = qy; pp[2] = qz;
    }
    float bv = -1.0f;
    int bj = 0;
#pragma unroll
    for (int j = 0; j < NPL; ++j) {
      float ddx = __fsub_rn(x[j], qx);
      float ddy = __fsub_rn(y[j], qy);
      float ddz = __fsub_rn(z[j], qz);
      float d = __fadd_rn(__fadd_rn(__fmul_rn(ddx, ddx), __fmul_rn(ddy, ddy)),
                          __fmul_rn(ddz, ddz));
      float nd = fminf(dist[j], d);
      dist[j] = nd;
      if (nd > bv) { bv = nd; bj = j; }
    }
    int bg = lane * NPL + bj;
#pragma unroll
    for (int off = 32; off >= 1; off >>= 1) {
      float ov = __shfl_xor(bv, off);
      int og = __shfl_xor(bg, off);
      if (ov > bv || (ov == bv && og < bg)) { bv = ov; bg = og; }
    }
    cur = bg;
    if (lane == 0) idx_out[b * k_out + t] = cur;
  }
  if (lane == 0) {
    float* pp = pos_out + ((size_t)b * k_out + (k_out - 1)) * 3;
    pp[0] = X[cur]; pp[1] = Y[cur]; pp[2] = Z[cur];
  }
}

// ---------------- level-1 ball conv: 1 block per target, sparse neighbors ----------------
__global__ __launch_bounds__(128) void conv1_kernel(
    const float* __restrict__ pos1,
    const float* __restrict__ w1, const float* __restrict__ b1,
    const float* __restrict__ g, const float* __restrict__ beta,
    const float* __restrict__ m, const float* __restrict__ v,
    const float* __restrict__ w2, const float* __restrict__ b2,
    float* __restrict__ x1out) {
  const int b = blockIdx.x >> 10;
  const int i = blockIdx.x & 1023;
  const int c = threadIdx.x;
  __shared__ int nbr[64];
  __shared__ int cnt;
  __shared__ float hbuf[128];
  const float* pb = pos1 + (size_t)b * 1024 * 3;
  const float xi = pb[i * 3 + 0], yi = pb[i * 3 + 1], zi = pb[i * 3 + 2];
  if (c == 0) cnt = 0;
  __syncthreads();
  const float rr = (float)(0.1 * 0.1);  // matches jax weak-typed r*r rounding
#pragma unroll
  for (int k = 0; k < 8; ++k) {
    int j = c + (k << 7);
    float ddx = __fsub_rn(xi, pb[j * 3 + 0]);
    float ddy = __fsub_rn(yi, pb[j * 3 + 1]);
    float ddz = __fsub_rn(zi, pb[j * 3 + 2]);
    float d2 = __fadd_rn(__fadd_rn(__fmul_rn(ddx, ddx), __fmul_rn(ddy, ddy)),
                         __fmul_rn(ddz, ddz));
    if (d2 <= rr) {
      int s = atomicAdd(&cnt, 1);
      if (s < 64) nbr[s] = j;
    }
  }
  __syncthreads();
  const int n = min(cnt, 64);
  const float scale = g[c] / sqrtf(v[c] + 1e-5f);
  const float shift = beta[c] - m[c] * scale;
  float w1c[6];
#pragma unroll
  for (int f = 0; f < 6; ++f) w1c[f] = w1[f * 128 + c];
  const float b1c = b1[c], b2c = b2[c];
  float acc = 0.0f;  // all candidates are relu() >= 0 and self is always valid
  for (int q = 0; q < n; ++q) {
    const int j = nbr[q];
    const float fx = pb[j * 3 + 0], fy = pb[j * 3 + 1], fz = pb[j * 3 + 2];
    float h = b1c;
    h = fmaf(fx, w1c[0], h);
    h = fmaf(fy, w1c[1], h);
    h = fmaf(fz, w1c[2], h);
    h = fmaf(fx - xi, w1c[3], h);
    h = fmaf(fy - yi, w1c[4], h);
    h = fmaf(fz - zi, w1c[5], h);
    h = fmaxf(fmaf(h, scale, shift), 0.0f);
    hbuf[c] = h;
    __syncthreads();
    float o = b2c;
#pragma unroll 8
    for (int k2 = 0; k2 < 128; ++k2) o = fmaf(hbuf[k2], w2[(k2 << 7) + c], o);
    acc = fmaxf(acc, fmaxf(o, 0.0f));
    __syncthreads();
  }
  x1out[((size_t)(b * 1024 + i)) * 128 + c] = acc;
}

// ---------------- level-2 ball conv ----------------
__global__ __launch_bounds__(256) void conv2_kernel(
    const float* __restrict__ pos2, const int* __restrict__ idx2,
    const float* __restrict__ x1,
    const float* __restrict__ w1, const float* __restrict__ b1,
    const float* __restrict__ g, const float* __restrict__ beta,
    const float* __restrict__ m, const float* __restrict__ v,
    const float* __restrict__ w2, const float* __restrict__ b2,
    float* __restrict__ out) {
  const int b = blockIdx.x >> 9;
  const int i = blockIdx.x & 511;
  const int c = threadIdx.x;  // 0..255
  __shared__ int nbr[64];
  __shared__ int cnt;
  __shared__ float xj[128];
  __shared__ float hbuf[256];
  const float* pb = pos2 + (size_t)b * 512 * 3;
  const float xi = pb[i * 3 + 0], yi = pb[i * 3 + 1], zi = pb[i * 3 + 2];
  if (c == 0) cnt = 0;
  __syncthreads();
  const float rr = (float)(0.25 * 0.25);
#pragma unroll
  for (int k = 0; k < 2; ++k) {
    int j = c + (k << 8);
    float ddx = __fsub_rn(xi, pb[j * 3 + 0]);
    float ddy = __fsub_rn(yi, pb[j * 3 + 1]);
    float ddz = __fsub_rn(zi, pb[j * 3 + 2]);
    float d2 = __fadd_rn(__fadd_rn(__fmul_rn(ddx, ddx), __fmul_rn(ddy, ddy)),
                         __fmul_rn(ddz, ddz));
    if (d2 <= rr) {
      int s = atomicAdd(&cnt, 1);
      if (s < 64) nbr[s] = j;
    }
  }
  __syncthreads();
  const int n = min(cnt, 64);
  const float scale = g[c] / sqrtf(v[c] + 1e-5f);
  const float shift = beta[c] - m[c] * scale;
  const float b1c = b1[c];
  const float b2c0 = b2[c], b2c1 = b2[c + 256];
  float acc0 = 0.0f, acc1 = 0.0f;
  for (int q = 0; q < n; ++q) {
    const int j = nbr[q];
    const int src = idx2[b * 512 + j];
    if (c < 128) xj[c] = x1[((size_t)b * 1024 + src) * 128 + c];
    const float fx = pb[j * 3 + 0], fy = pb[j * 3 + 1], fz = pb[j * 3 + 2];
    const float r0 = fx - xi, r1 = fy - yi, r2 = fz - zi;
    __syncthreads();
    float h = b1c;
#pragma unroll 8
    for (int f = 0; f < 128; ++f) h = fmaf(xj[f], w1[f * 256 + c], h);
    h = fmaf(r0, w1[128 * 256 + c], h);
    h = fmaf(r1, w1[129 * 256 + c], h);
    h = fmaf(r2, w1[130 * 256 + c], h);
    h = fmaxf(fmaf(h, scale, shift), 0.0f);
    hbuf[c] = h;
    __syncthreads();
    float o0 = b2c0, o1 = b2c1;
#pragma unroll 8
    for (int k2 = 0; k2 < 256; ++k2) {
      float hk = hbuf[k2];
      o0 = fmaf(hk, w2[k2 * 512 + c], o0);
      o1 = fmaf(hk, w2[k2 * 512 + c + 256], o1);
    }
    acc0 = fmaxf(acc0, fmaxf(o0, 0.0f));
    acc1 = fmaxf(acc1, fmaxf(o1, 0.0f));
    __syncthreads();
  }
  float* ob = out + ((size_t)(b * 512 + i)) * 512;
  ob[c] = acc0;
  ob[c + 256] = acc1;
}

// ---------------- batch ids (written as float; harness reads d_out as f32) ----------------
__global__ __launch_bounds__(256) void batch_fill_kernel(float* __restrict__ out) {
  int t = blockIdx.x * 256 + threadIdx.x;  // 0..4095
  out[t] = (float)(t >> 9);
}

extern "C" void kernel_launch(void* const* d_in, const int* in_sizes, int n_in,
                              void* d_out, int out_size, void* d_ws, size_t ws_size,
                              hipStream_t stream) {
  const float* pos    = (const float*)d_in[0];
  const float* c1_w1  = (const float*)d_in[1];
  const float* c1_b1  = (const float*)d_in[2];
  const float* c1_g   = (const float*)d_in[3];
  const float* c1_be  = (const float*)d_in[4];
  const float* c1_m   = (const float*)d_in[5];
  const float* c1_v   = (const float*)d_in[6];
  const float* c1_w2  = (const float*)d_in[7];
  const float* c1_b2  = (const float*)d_in[8];
  const float* c2_w1  = (const float*)d_in[9];
  const float* c2_b1  = (const float*)d_in[10];
  const float* c2_g   = (const float*)d_in[11];
  const float* c2_be  = (const float*)d_in[12];
  const float* c2_m   = (const float*)d_in[13];
  const float* c2_v   = (const float*)d_in[14];
  const float* c2_w2  = (const float*)d_in[15];
  const float* c2_b2  = (const float*)d_in[16];

  char* ws = (char*)d_ws;
  float* pnorm = (float*)(ws + 0);        // 8*2048*3*4   = 196608
  float* pos1  = (float*)(ws + 196608);   // 8*1024*3*4   =  98304
  int*   idx1  = (int*)  (ws + 294912);   // 8*1024*4     =  32768
  float* pos2  = (float*)(ws + 327680);   // 8*512*3*4    =  49152
  int*   idx2  = (int*)  (ws + 376832);   // 8*512*4      =  16384
  float* x1    = (float*)(ws + 393216);   // 8*1024*128*4 = 4194304  (end 4587520)
  float* out   = (float*)d_out;

  normalize_kernel<<<8, 256, 0, stream>>>(pos, pnorm);
  fps_kernel<32><<<8, 64, 0, stream>>>(pnorm, 1024, idx1, pos1);
  fps_kernel<16><<<8, 64, 0, stream>>>(pos1, 512, idx2, pos2);
  conv1_kernel<<<8 * 1024, 128, 0, stream>>>(pos1, c1_w1, c1_b1, c1_g, c1_be,
                                             c1_m, c1_v, c1_w2, c1_b2, x1);
  conv2_kernel<<<8 * 512, 256, 0, stream>>>(pos2, idx2, x1, c2_w1, c2_b1, c2_g,
                                            c2_be, c2_m, c2_v, c2_w2, c2_b2, out);
  batch_fill_kernel<<<16, 256, 0, stream>>>(out + 2097152);
}

// Round 2
// 1595.324 us; speedup vs baseline: 1.1014x; 1.1014x over previous
//
#include <hip/hip_runtime.h>

#define B_ 8
#define N_ 2048

// ---------------- DPP argmax merge: max value, tie -> smallest global index ----------------
template <int CTRL>
__device__ __forceinline__ void merge2(float& bv, int& bg) {
  int ovi = __builtin_amdgcn_update_dpp(__float_as_int(-1.0f), __float_as_int(bv),
                                        CTRL, 0xF, 0xF, false);
  int og  = __builtin_amdgcn_update_dpp(0x7fffffff, bg, CTRL, 0xF, 0xF, false);
  float ov = __int_as_float(ovi);
  bool p = (ov > bv) || ((ov == bv) && (og < bg));
  bv = p ? ov : bv;
  bg = p ? og : bg;
}

// ---------------- farthest point sampling body: ONE wave, points in LDS+regs ----------------
// Bit-exact vs reference: ((dx*dx+dy*dy)+dz*dz) via _rn ops, fminf update,
// strict > keeps first index within lane; cross-lane tie-break by smaller index.
template <int NPL>
__device__ __forceinline__ void fps_body(const float* __restrict__ S,  // LDS xyz interleaved
                                         float (&x)[NPL], float (&y)[NPL], float (&z)[NPL],
                                         int lane, int k_out,
                                         int* __restrict__ idx_out,
                                         float* __restrict__ pos_out) {
  float dist[NPL];
#pragma unroll
  for (int j = 0; j < NPL; ++j) dist[j] = 1e10f;
  float qx = S[0], qy = S[1], qz = S[2];  // deterministic start at index 0
  if (lane == 0) {
    pos_out[0] = qx; pos_out[1] = qy; pos_out[2] = qz;
    if (idx_out) idx_out[0] = 0;
  }
  const int gbase = lane * NPL;
  for (int t = 1; t < k_out; ++t) {
    float bv = -1.0f;
    int bg = 0x7fffffff;
#pragma unroll
    for (int j = 0; j < NPL; ++j) {
      float ddx = __fsub_rn(x[j], qx);
      float ddy = __fsub_rn(y[j], qy);
      float ddz = __fsub_rn(z[j], qz);
      float d = __fadd_rn(__fadd_rn(__fmul_rn(ddx, ddx), __fmul_rn(ddy, ddy)),
                          __fmul_rn(ddz, ddz));
      float nd = fminf(dist[j], d);
      dist[j] = nd;
      bool pr = nd > bv;
      bv = pr ? nd : bv;
      bg = pr ? (gbase + j) : bg;
    }
    // wave64 reduce via DPP (no DS traffic); result lands in lane 63
    merge2<0x111>(bv, bg);  // row_shr:1
    merge2<0x112>(bv, bg);  // row_shr:2
    merge2<0x114>(bv, bg);  // row_shr:4
    merge2<0x118>(bv, bg);  // row_shr:8
    merge2<0x142>(bv, bg);  // row_bcast:15
    merge2<0x143>(bv, bg);  // row_bcast:31
    int cur = __builtin_amdgcn_readlane(bg, 63);
    qx = S[cur * 3 + 0]; qy = S[cur * 3 + 1]; qz = S[cur * 3 + 2];
    if (lane == 0) {
      float* pp = pos_out + t * 3;
      pp[0] = qx; pp[1] = qy; pp[2] = qz;
      if (idx_out) idx_out[t] = cur;
    }
  }
}

// ---------------- fused normalize (f64 stats, fp32 ops match np) + FPS level 1 ----------------
__global__ __launch_bounds__(256) void norm_fps1_kernel(const float* __restrict__ pos,
                                                        float* __restrict__ pos1) {
  __shared__ float S[N_ * 3];
  __shared__ double wsum[3][4];
  __shared__ float bc[6];
  const int b = blockIdx.x, tid = threadIdx.x;
  const float* base = pos + (size_t)b * N_ * 3;
  float px[8], py[8], pz[8];
  double sx = 0.0, sy = 0.0, sz = 0.0;
#pragma unroll
  for (int k = 0; k < 8; ++k) {
    int g = tid * 8 + k;
    px[k] = base[g * 3 + 0];
    py[k] = base[g * 3 + 1];
    pz[k] = base[g * 3 + 2];
    sx += (double)px[k]; sy += (double)py[k]; sz += (double)pz[k];
  }
  const int wid = tid >> 6, lid = tid & 63;
#pragma unroll
  for (int off = 32; off >= 1; off >>= 1) {
    sx += __shfl_down(sx, off);
    sy += __shfl_down(sy, off);
    sz += __shfl_down(sz, off);
  }
  if (lid == 0) { wsum[0][wid] = sx; wsum[1][wid] = sy; wsum[2][wid] = sz; }
  __syncthreads();
  if (tid == 0) {
    bc[0] = (float)((wsum[0][0] + wsum[0][1] + wsum[0][2] + wsum[0][3]) / 2048.0);
    bc[1] = (float)((wsum[1][0] + wsum[1][1] + wsum[1][2] + wsum[1][3]) / 2048.0);
    bc[2] = (float)((wsum[2][0] + wsum[2][1] + wsum[2][2] + wsum[2][3]) / 2048.0);
  }
  __syncthreads();
  const float mx = bc[0], my = bc[1], mz = bc[2];
  float dx[8], dy[8], dz[8];
  double qx = 0.0, qy = 0.0, qz = 0.0;
#pragma unroll
  for (int k = 0; k < 8; ++k) {
    dx[k] = __fsub_rn(px[k], mx);
    dy[k] = __fsub_rn(py[k], my);
    dz[k] = __fsub_rn(pz[k], mz);
    qx += (double)__fmul_rn(dx[k], dx[k]);
    qy += (double)__fmul_rn(dy[k], dy[k]);
    qz += (double)__fmul_rn(dz[k], dz[k]);
  }
#pragma unroll
  for (int off = 32; off >= 1; off >>= 1) {
    qx += __shfl_down(qx, off);
    qy += __shfl_down(qy, off);
    qz += __shfl_down(qz, off);
  }
  if (lid == 0) { wsum[0][wid] = qx; wsum[1][wid] = qy; wsum[2][wid] = qz; }
  __syncthreads();
  if (tid == 0) {
    bc[3] = __fadd_rn(__fsqrt_rn((float)((wsum[0][0]+wsum[0][1]+wsum[0][2]+wsum[0][3]) / 2047.0)), 1e-6f);
    bc[4] = __fadd_rn(__fsqrt_rn((float)((wsum[1][0]+wsum[1][1]+wsum[1][2]+wsum[1][3]) / 2047.0)), 1e-6f);
    bc[5] = __fadd_rn(__fsqrt_rn((float)((wsum[2][0]+wsum[2][1]+wsum[2][2]+wsum[2][3]) / 2047.0)), 1e-6f);
  }
  __syncthreads();
  const float isx = bc[3], isy = bc[4], isz = bc[5];
#pragma unroll
  for (int k = 0; k < 8; ++k) {
    int g = tid * 8 + k;
    S[g * 3 + 0] = __fdiv_rn(dx[k], isx);
    S[g * 3 + 1] = __fdiv_rn(dy[k], isy);
    S[g * 3 + 2] = __fdiv_rn(dz[k], isz);
  }
  __syncthreads();          // all threads reach this; then waves 1-3 exit
  if (tid >= 64) return;    // single wave from here on: no more barriers
  float x[32], y[32], z[32];
#pragma unroll
  for (int j = 0; j < 32; ++j) {
    int g = tid * 32 + j;
    x[j] = S[g * 3 + 0]; y[j] = S[g * 3 + 1]; z[j] = S[g * 3 + 2];
  }
  fps_body<32>(S, x, y, z, tid, 1024, nullptr, pos1 + (size_t)b * 1024 * 3);
}

// ---------------- fused: conv1 (blocks 0..8191) + FPS level 2 (blocks 8192..8199) ----------------
__global__ __launch_bounds__(128) void mid_kernel(
    const float* __restrict__ pos1,
    const float* __restrict__ w1, const float* __restrict__ b1,
    const float* __restrict__ g, const float* __restrict__ beta,
    const float* __restrict__ m, const float* __restrict__ v,
    const float* __restrict__ w2, const float* __restrict__ b2,
    float* __restrict__ x1out,
    int* __restrict__ idx2, float* __restrict__ pos2) {
  __shared__ union U {
    struct { int nbr[64]; int cnt; float hbuf[128]; } c;
    float S[1024 * 3];
  } u;
  if (blockIdx.x < 8192) {
    // ---- conv1: one block per target point, sparse neighbor scan ----
    const int b = blockIdx.x >> 10;
    const int i = blockIdx.x & 1023;
    const int c = threadIdx.x;
    const float* pb = pos1 + (size_t)b * 1024 * 3;
    const float xi = pb[i * 3 + 0], yi = pb[i * 3 + 1], zi = pb[i * 3 + 2];
    if (c == 0) u.c.cnt = 0;
    __syncthreads();
    const float rr = (float)(0.1 * 0.1);  // matches weak-typed r*r rounding
#pragma unroll
    for (int k = 0; k < 8; ++k) {
      int j = c + (k << 7);
      float ddx = __fsub_rn(xi, pb[j * 3 + 0]);
      float ddy = __fsub_rn(yi, pb[j * 3 + 1]);
      float ddz = __fsub_rn(zi, pb[j * 3 + 2]);
      float d2 = __fadd_rn(__fadd_rn(__fmul_rn(ddx, ddx), __fmul_rn(ddy, ddy)),
                           __fmul_rn(ddz, ddz));
      if (d2 <= rr) {
        int s = atomicAdd(&u.c.cnt, 1);
        if (s < 64) u.c.nbr[s] = j;
      }
    }
    __syncthreads();
    const int n = min(u.c.cnt, 64);
    const float scale = g[c] / sqrtf(v[c] + 1e-5f);
    const float shift = beta[c] - m[c] * scale;
    float w1c[6];
#pragma unroll
    for (int f = 0; f < 6; ++f) w1c[f] = w1[f * 128 + c];
    const float b1c = b1[c], b2c = b2[c];
    float acc = 0.0f;  // relu >= 0 and self always valid
    for (int q = 0; q < n; ++q) {
      const int j = u.c.nbr[q];
      const float fx = pb[j * 3 + 0], fy = pb[j * 3 + 1], fz = pb[j * 3 + 2];
      float h = b1c;
      h = fmaf(fx, w1c[0], h);
      h = fmaf(fy, w1c[1], h);
      h = fmaf(fz, w1c[2], h);
      h = fmaf(fx - xi, w1c[3], h);
      h = fmaf(fy - yi, w1c[4], h);
      h = fmaf(fz - zi, w1c[5], h);
      h = fmaxf(fmaf(h, scale, shift), 0.0f);
      u.c.hbuf[c] = h;
      __syncthreads();
      float o = b2c;
#pragma unroll 8
      for (int k2 = 0; k2 < 128; ++k2) o = fmaf(u.c.hbuf[k2], w2[(k2 << 7) + c], o);
      acc = fmaxf(acc, fmaxf(o, 0.0f));
      __syncthreads();
    }
    x1out[((size_t)(b * 1024 + i)) * 128 + c] = acc;
  } else {
    // ---- fps2: 1024 -> 512, one wave ----
    if (threadIdx.x >= 64) return;  // wave 1 exits; no barriers below
    const int b = blockIdx.x - 8192;
    const int lane = threadIdx.x;
    const float* base = pos1 + (size_t)b * 1024 * 3;
    float x[16], y[16], z[16];
#pragma unroll
    for (int j = 0; j < 16; ++j) {
      int gg = lane * 16 + j;
      x[j] = base[gg * 3 + 0]; y[j] = base[gg * 3 + 1]; z[j] = base[gg * 3 + 2];
      u.S[gg * 3 + 0] = x[j]; u.S[gg * 3 + 1] = y[j]; u.S[gg * 3 + 2] = z[j];
    }
    fps_body<16>(u.S, x, y, z, lane, 512, idx2 + b * 512, pos2 + (size_t)b * 512 * 3);
  }
}

// ---------------- level-2 ball conv (+ batch-id epilogue) ----------------
__global__ __launch_bounds__(256) void conv2_kernel(
    const float* __restrict__ pos2, const int* __restrict__ idx2,
    const float* __restrict__ x1,
    const float* __restrict__ w1, const float* __restrict__ b1,
    const float* __restrict__ g, const float* __restrict__ beta,
    const float* __restrict__ m, const float* __restrict__ v,
    const float* __restrict__ w2, const float* __restrict__ b2,
    float* __restrict__ out, float* __restrict__ bout) {
  const int b = blockIdx.x >> 9;
  const int i = blockIdx.x & 511;
  const int c = threadIdx.x;  // 0..255
  __shared__ int nbr[64];
  __shared__ int cnt;
  __shared__ float xj[128];
  __shared__ float hbuf[256];
  const float* pb = pos2 + (size_t)b * 512 * 3;
  const float xi = pb[i * 3 + 0], yi = pb[i * 3 + 1], zi = pb[i * 3 + 2];
  if (c == 0) cnt = 0;
  __syncthreads();
  const float rr = (float)(0.25 * 0.25);
#pragma unroll
  for (int k = 0; k < 2; ++k) {
    int j = c + (k << 8);
    float ddx = __fsub_rn(xi, pb[j * 3 + 0]);
    float ddy = __fsub_rn(yi, pb[j * 3 + 1]);
    float ddz = __fsub_rn(zi, pb[j * 3 + 2]);
    float d2 = __fadd_rn(__fadd_rn(__fmul_rn(ddx, ddx), __fmul_rn(ddy, ddy)),
                         __fmul_rn(ddz, ddz));
    if (d2 <= rr) {
      int s = atomicAdd(&cnt, 1);
      if (s < 64) nbr[s] = j;
    }
  }
  __syncthreads();
  const int n = min(cnt, 64);
  const float scale = g[c] / sqrtf(v[c] + 1e-5f);
  const float shift = beta[c] - m[c] * scale;
  const float b1c = b1[c];
  const float b2c0 = b2[c], b2c1 = b2[c + 256];
  float acc0 = 0.0f, acc1 = 0.0f;
  for (int q = 0; q < n; ++q) {
    const int j = nbr[q];
    const int src = idx2[b * 512 + j];
    if (c < 128) xj[c] = x1[((size_t)b * 1024 + src) * 128 + c];
    const float fx = pb[j * 3 + 0], fy = pb[j * 3 + 1], fz = pb[j * 3 + 2];
    const float r0 = fx - xi, r1 = fy - yi, r2 = fz - zi;
    __syncthreads();
    float h = b1c;
#pragma unroll 8
    for (int f = 0; f < 128; ++f) h = fmaf(xj[f], w1[f * 256 + c], h);
    h = fmaf(r0, w1[128 * 256 + c], h);
    h = fmaf(r1, w1[129 * 256 + c], h);
    h = fmaf(r2, w1[130 * 256 + c], h);
    h = fmaxf(fmaf(h, scale, shift), 0.0f);
    hbuf[c] = h;
    __syncthreads();
    float o0 = b2c0, o1 = b2c1;
#pragma unroll 8
    for (int k2 = 0; k2 < 256; ++k2) {
      float hk = hbuf[k2];
      o0 = fmaf(hk, w2[k2 * 512 + c], o0);
      o1 = fmaf(hk, w2[k2 * 512 + c + 256], o1);
    }
    acc0 = fmaxf(acc0, fmaxf(o0, 0.0f));
    acc1 = fmaxf(acc1, fmaxf(o1, 0.0f));
    __syncthreads();
  }
  float* ob = out + ((size_t)(b * 512 + i)) * 512;
  ob[c] = acc0;
  ob[c + 256] = acc1;
  if (c == 0) bout[b * 512 + i] = (float)b;  // batch ids as f32
}

extern "C" void kernel_launch(void* const* d_in, const int* in_sizes, int n_in,
                              void* d_out, int out_size, void* d_ws, size_t ws_size,
                              hipStream_t stream) {
  const float* pos    = (const float*)d_in[0];
  const float* c1_w1  = (const float*)d_in[1];
  const float* c1_b1  = (const float*)d_in[2];
  const float* c1_g   = (const float*)d_in[3];
  const float* c1_be  = (const float*)d_in[4];
  const float* c1_m   = (const float*)d_in[5];
  const float* c1_v   = (const float*)d_in[6];
  const float* c1_w2  = (const float*)d_in[7];
  const float* c1_b2  = (const float*)d_in[8];
  const float* c2_w1  = (const float*)d_in[9];
  const float* c2_b1  = (const float*)d_in[10];
  const float* c2_g   = (const float*)d_in[11];
  const float* c2_be  = (const float*)d_in[12];
  const float* c2_m   = (const float*)d_in[13];
  const float* c2_v   = (const float*)d_in[14];
  const float* c2_w2  = (const float*)d_in[15];
  const float* c2_b2  = (const float*)d_in[16];

  char* ws = (char*)d_ws;
  float* pos1 = (float*)(ws + 0);        // 8*1024*3*4 =  98304
  int*   idx2 = (int*)  (ws + 98304);    // 8*512*4    =  16384
  float* pos2 = (float*)(ws + 114688);   // 8*512*3*4  =  49152
  float* x1   = (float*)(ws + 163840);   // 8*1024*128*4 = 4194304 (end 4358144)
  float* out  = (float*)d_out;

  norm_fps1_kernel<<<8, 256, 0, stream>>>(pos, pos1);
  mid_kernel<<<8192 + 8, 128, 0, stream>>>(pos1, c1_w1, c1_b1, c1_g, c1_be,
                                           c1_m, c1_v, c1_w2, c1_b2, x1, idx2, pos2);
  conv2_kernel<<<4096, 256, 0, stream>>>(pos2, idx2, x1, c2_w1, c2_b1, c2_g,
                                         c2_be, c2_m, c2_v, c2_w2, c2_b2, out,
                                         out + 2097152);
}

// Round 3
// 1552.596 us; speedup vs baseline: 1.1318x; 1.0275x over previous
//
#include <hip/hip_runtime.h>

#define B_ 8
#define N_ 2048

// merge (b) into (a): max value, tie -> smaller global index (jnp.argmax first-index)
__device__ __forceinline__ void mergeT(float& av, int& ag, float& ax, float& ay, float& az,
                                       float bv, int bg, float bx, float by, float bz) {
  bool p = (bv > av) || ((bv == av) && (bg < ag));
  av = p ? bv : av;
  ag = p ? bg : ag;
  ax = p ? bx : ax;
  ay = p ? by : ay;
  az = p ? bz : az;
}

template <int CTRL>
__device__ __forceinline__ void dppMerge(float& bv, int& bg) {
  int ovi = __builtin_amdgcn_update_dpp(__float_as_int(-1.0f), __float_as_int(bv),
                                        CTRL, 0xF, 0xF, false);
  int og  = __builtin_amdgcn_update_dpp(0x7fffffff, bg, CTRL, 0xF, 0xF, false);
  float ov = __int_as_float(ovi);
  bool p = (ov > bv) || ((ov == bv) && (og < bg));
  bv = p ? ov : bv;
  bg = p ? og : bg;
}

// ---------------- multi-wave FPS loop: 256 threads, P points per thread ----------------
// Bit-exact distances: ((dx*dx+dy*dy)+dz*dz) via _rn ops, fminf update.
// One __syncthreads per iteration (double-buffered reduce slots).
template <int P>
__device__ __forceinline__ void fps_loop(float (&x)[P], float (&y)[P], float (&z)[P],
                                         float qx, float qy, float qz,
                                         int k_out, int tid,
                                         float (*red)[4][8],          // [2][4][8] LDS
                                         float* __restrict__ S1,      // LDS mirror or nullptr
                                         float* __restrict__ pos_out, // global
                                         int* __restrict__ idx_out) { // global or nullptr
  float dist[P];
#pragma unroll
  for (int j = 0; j < P; ++j) dist[j] = 1e10f;
  const int gbase = tid * P;
  const int wid = tid >> 6;
  for (int t = 1; t < k_out; ++t) {
    float tv[P]; int tg[P]; float tx[P], ty[P], tz[P];
#pragma unroll
    for (int j = 0; j < P; ++j) {
      float ddx = __fsub_rn(x[j], qx);
      float ddy = __fsub_rn(y[j], qy);
      float ddz = __fsub_rn(z[j], qz);
      float d = __fadd_rn(__fadd_rn(__fmul_rn(ddx, ddx), __fmul_rn(ddy, ddy)),
                          __fmul_rn(ddz, ddz));
      float nd = fminf(dist[j], d);
      dist[j] = nd;
      tv[j] = nd; tg[j] = gbase + j; tx[j] = x[j]; ty[j] = y[j]; tz[j] = z[j];
    }
    // in-lane tree argmax (short dependence chains)
#pragma unroll
    for (int s = 1; s < P; s <<= 1)
#pragma unroll
      for (int j = 0; j < P; j += (s << 1))
        mergeT(tv[j], tg[j], tx[j], ty[j], tz[j],
               tv[j + s], tg[j + s], tx[j + s], ty[j + s], tz[j + s]);
    // wave64 reduce via DPP on (value, global idx); result in lane 63
    float dv = tv[0]; int dg = tg[0];
    dppMerge<0x111>(dv, dg);  // row_shr:1
    dppMerge<0x112>(dv, dg);  // row_shr:2
    dppMerge<0x114>(dv, dg);  // row_shr:4
    dppMerge<0x118>(dv, dg);  // row_shr:8
    dppMerge<0x142>(dv, dg);  // row_bcast:15
    dppMerge<0x143>(dv, dg);  // row_bcast:31
    const int gw = __builtin_amdgcn_readlane(dg, 63);
    const int par = t & 1;
    if (tg[0] == gw) {  // exactly one lane per wave: the wave-winner owner
      float* slot = &red[par][wid][0];
      ((float4*)slot)[0] = make_float4(tv[0], __int_as_float(tg[0]), tx[0], ty[0]);
      slot[4] = tz[0];
    }
    __syncthreads();
    // merge the 4 wave slots (coords ride along: no dependent S[cur] fetch)
    const float* s0 = &red[par][0][0];
    float4 a0 = ((const float4*)s0)[0];
    float av = a0.x; int ag = __float_as_int(a0.y);
    float ax = a0.z, ay = a0.w, az = s0[4];
#pragma unroll
    for (int w = 1; w < 4; ++w) {
      const float* sw = &red[par][w][0];
      float4 bq = ((const float4*)sw)[0];
      mergeT(av, ag, ax, ay, az, bq.x, __float_as_int(bq.y), bq.z, bq.w, sw[4]);
    }
    qx = ax; qy = ay; qz = az;
    if (tid == 0) {
      float* pp = pos_out + t * 3;
      pp[0] = qx; pp[1] = qy; pp[2] = qz;
      if (S1) { S1[t * 3 + 0] = qx; S1[t * 3 + 1] = qy; S1[t * 3 + 2] = qz; }
      if (idx_out) idx_out[t] = ag;
    }
  }
}

// ---------------- fused: normalize (f64 stats) + FPS level 1 + FPS level 2 ----------------
__global__ __launch_bounds__(256, 1) void fused_fps_kernel(const float* __restrict__ pos,
                                                           float* __restrict__ pos1,
                                                           float* __restrict__ pos2,
                                                           int* __restrict__ idx2) {
  __shared__ float S1[1024 * 3];      // pos1 mirror for fps2 ownership loads
  __shared__ float red[2][4][8];      // double-buffered per-wave reduce slots
  __shared__ double wsum[3][4];
  __shared__ float bc[6];
  __shared__ float q0[3];
  const int b = blockIdx.x, tid = threadIdx.x;
  const float* base = pos + (size_t)b * N_ * 3;
  float px[8], py[8], pz[8];
  double sx = 0.0, sy = 0.0, sz = 0.0;
#pragma unroll
  for (int k = 0; k < 8; ++k) {
    int g = tid * 8 + k;
    px[k] = base[g * 3 + 0];
    py[k] = base[g * 3 + 1];
    pz[k] = base[g * 3 + 2];
    sx += (double)px[k]; sy += (double)py[k]; sz += (double)pz[k];
  }
  const int wid = tid >> 6, lid = tid & 63;
#pragma unroll
  for (int off = 32; off >= 1; off >>= 1) {
    sx += __shfl_down(sx, off);
    sy += __shfl_down(sy, off);
    sz += __shfl_down(sz, off);
  }
  if (lid == 0) { wsum[0][wid] = sx; wsum[1][wid] = sy; wsum[2][wid] = sz; }
  __syncthreads();
  if (tid == 0) {
    bc[0] = (float)((wsum[0][0] + wsum[0][1] + wsum[0][2] + wsum[0][3]) / 2048.0);
    bc[1] = (float)((wsum[1][0] + wsum[1][1] + wsum[1][2] + wsum[1][3]) / 2048.0);
    bc[2] = (float)((wsum[2][0] + wsum[2][1] + wsum[2][2] + wsum[2][3]) / 2048.0);
  }
  __syncthreads();
  const float mx = bc[0], my = bc[1], mz = bc[2];
  float dx[8], dy[8], dz[8];
  double qxs = 0.0, qys = 0.0, qzs = 0.0;
#pragma unroll
  for (int k = 0; k < 8; ++k) {
    dx[k] = __fsub_rn(px[k], mx);
    dy[k] = __fsub_rn(py[k], my);
    dz[k] = __fsub_rn(pz[k], mz);
    qxs += (double)__fmul_rn(dx[k], dx[k]);
    qys += (double)__fmul_rn(dy[k], dy[k]);
    qzs += (double)__fmul_rn(dz[k], dz[k]);
  }
#pragma unroll
  for (int off = 32; off >= 1; off >>= 1) {
    qxs += __shfl_down(qxs, off);
    qys += __shfl_down(qys, off);
    qzs += __shfl_down(qzs, off);
  }
  if (lid == 0) { wsum[0][wid] = qxs; wsum[1][wid] = qys; wsum[2][wid] = qzs; }
  __syncthreads();
  if (tid == 0) {
    bc[3] = __fadd_rn(__fsqrt_rn((float)((wsum[0][0]+wsum[0][1]+wsum[0][2]+wsum[0][3]) / 2047.0)), 1e-6f);
    bc[4] = __fadd_rn(__fsqrt_rn((float)((wsum[1][0]+wsum[1][1]+wsum[1][2]+wsum[1][3]) / 2047.0)), 1e-6f);
    bc[5] = __fadd_rn(__fsqrt_rn((float)((wsum[2][0]+wsum[2][1]+wsum[2][2]+wsum[2][3]) / 2047.0)), 1e-6f);
  }
  __syncthreads();
  const float isx = bc[3], isy = bc[4], isz = bc[5];
  float xn[8], yn[8], zn[8];
#pragma unroll
  for (int k = 0; k < 8; ++k) {
    xn[k] = __fdiv_rn(dx[k], isx);
    yn[k] = __fdiv_rn(dy[k], isy);
    zn[k] = __fdiv_rn(dz[k], isz);
  }
  float* p1b = pos1 + (size_t)b * 1024 * 3;
  if (tid == 0) {  // point 0 (deterministic FPS start) broadcast + outputs
    q0[0] = xn[0]; q0[1] = yn[0]; q0[2] = zn[0];
    S1[0] = xn[0]; S1[1] = yn[0]; S1[2] = zn[0];
    p1b[0] = xn[0]; p1b[1] = yn[0]; p1b[2] = zn[0];
  }
  __syncthreads();
  // ---- FPS level 1: 2048 -> 1024 ----
  fps_loop<8>(xn, yn, zn, q0[0], q0[1], q0[2], 1024, tid, red, S1, p1b, nullptr);
  __syncthreads();  // S1 complete
  // ---- FPS level 2: 1024 -> 512 (ownership from S1 mirror) ----
  float x2[4], y2[4], z2[4];
#pragma unroll
  for (int s = 0; s < 4; ++s) {
    int g = tid * 4 + s;
    x2[s] = S1[g * 3 + 0]; y2[s] = S1[g * 3 + 1]; z2[s] = S1[g * 3 + 2];
  }
  float* p2b = pos2 + (size_t)b * 512 * 3;
  int* i2b = idx2 + b * 512;
  const float q2x = S1[0], q2y = S1[1], q2z = S1[2];
  if (tid == 0) {
    p2b[0] = q2x; p2b[1] = q2y; p2b[2] = q2z;
    i2b[0] = 0;
  }
  __syncthreads();
  fps_loop<4>(x2, y2, z2, q2x, q2y, q2z, 512, tid, red, nullptr, p2b, i2b);
}

// ---------------- level-1 ball conv: 1 block per target, sparse neighbors ----------------
__global__ __launch_bounds__(128) void conv1_kernel(
    const float* __restrict__ pos1,
    const float* __restrict__ w1, const float* __restrict__ b1,
    const float* __restrict__ g, const float* __restrict__ beta,
    const float* __restrict__ m, const float* __restrict__ v,
    const float* __restrict__ w2, const float* __restrict__ b2,
    float* __restrict__ x1out) {
  const int b = blockIdx.x >> 10;
  const int i = blockIdx.x & 1023;
  const int c = threadIdx.x;
  __shared__ int nbr[64];
  __shared__ int cnt;
  __shared__ float hbuf[128];
  const float* pb = pos1 + (size_t)b * 1024 * 3;
  const float xi = pb[i * 3 + 0], yi = pb[i * 3 + 1], zi = pb[i * 3 + 2];
  if (c == 0) cnt = 0;
  __syncthreads();
  const float rr = (float)(0.1 * 0.1);  // matches weak-typed r*r rounding
#pragma unroll
  for (int k = 0; k < 8; ++k) {
    int j = c + (k << 7);
    float ddx = __fsub_rn(xi, pb[j * 3 + 0]);
    float ddy = __fsub_rn(yi, pb[j * 3 + 1]);
    float ddz = __fsub_rn(zi, pb[j * 3 + 2]);
    float d2 = __fadd_rn(__fadd_rn(__fmul_rn(ddx, ddx), __fmul_rn(ddy, ddy)),
                         __fmul_rn(ddz, ddz));
    if (d2 <= rr) {
      int s = atomicAdd(&cnt, 1);
      if (s < 64) nbr[s] = j;
    }
  }
  __syncthreads();
  const int n = min(cnt, 64);
  const float scale = g[c] / sqrtf(v[c] + 1e-5f);
  const float shift = beta[c] - m[c] * scale;
  float w1c[6];
#pragma unroll
  for (int f = 0; f < 6; ++f) w1c[f] = w1[f * 128 + c];
  const float b1c = b1[c], b2c = b2[c];
  float acc = 0.0f;  // relu >= 0 and self always valid
  for (int q = 0; q < n; ++q) {
    const int j = nbr[q];
    const float fx = pb[j * 3 + 0], fy = pb[j * 3 + 1], fz = pb[j * 3 + 2];
    float h = b1c;
    h = fmaf(fx, w1c[0], h);
    h = fmaf(fy, w1c[1], h);
    h = fmaf(fz, w1c[2], h);
    h = fmaf(fx - xi, w1c[3], h);
    h = fmaf(fy - yi, w1c[4], h);
    h = fmaf(fz - zi, w1c[5], h);
    h = fmaxf(fmaf(h, scale, shift), 0.0f);
    hbuf[c] = h;
    __syncthreads();
    float o = b2c;
#pragma unroll 8
    for (int k2 = 0; k2 < 128; ++k2) o = fmaf(hbuf[k2], w2[(k2 << 7) + c], o);
    acc = fmaxf(acc, fmaxf(o, 0.0f));
    __syncthreads();
  }
  x1out[((size_t)(b * 1024 + i)) * 128 + c] = acc;
}

// ---------------- level-2 ball conv (+ batch-id epilogue) ----------------
__global__ __launch_bounds__(256) void conv2_kernel(
    const float* __restrict__ pos2, const int* __restrict__ idx2,
    const float* __restrict__ x1,
    const float* __restrict__ w1, const float* __restrict__ b1,
    const float* __restrict__ g, const float* __restrict__ beta,
    const float* __restrict__ m, const float* __restrict__ v,
    const float* __restrict__ w2, const float* __restrict__ b2,
    float* __restrict__ out, float* __restrict__ bout) {
  const int b = blockIdx.x >> 9;
  const int i = blockIdx.x & 511;
  const int c = threadIdx.x;  // 0..255
  __shared__ int nbr[64];
  __shared__ int cnt;
  __shared__ float xj[128];
  __shared__ float hbuf[256];
  const float* pb = pos2 + (size_t)b * 512 * 3;
  const float xi = pb[i * 3 + 0], yi = pb[i * 3 + 1], zi = pb[i * 3 + 2];
  if (c == 0) cnt = 0;
  __syncthreads();
  const float rr = (float)(0.25 * 0.25);
#pragma unroll
  for (int k = 0; k < 2; ++k) {
    int j = c + (k << 8);
    float ddx = __fsub_rn(xi, pb[j * 3 + 0]);
    float ddy = __fsub_rn(yi, pb[j * 3 + 1]);
    float ddz = __fsub_rn(zi, pb[j * 3 + 2]);
    float d2 = __fadd_rn(__fadd_rn(__fmul_rn(ddx, ddx), __fmul_rn(ddy, ddy)),
                         __fmul_rn(ddz, ddz));
    if (d2 <= rr) {
      int s = atomicAdd(&cnt, 1);
      if (s < 64) nbr[s] = j;
    }
  }
  __syncthreads();
  const int n = min(cnt, 64);
  const float scale = g[c] / sqrtf(v[c] + 1e-5f);
  const float shift = beta[c] - m[c] * scale;
  const float b1c = b1[c];
  const float b2c0 = b2[c], b2c1 = b2[c + 256];
  float acc0 = 0.0f, acc1 = 0.0f;
  for (int q = 0; q < n; ++q) {
    const int j = nbr[q];
    const int src = idx2[b * 512 + j];
    if (c < 128) xj[c] = x1[((size_t)b * 1024 + src) * 128 + c];
    const float fx = pb[j * 3 + 0], fy = pb[j * 3 + 1], fz = pb[j * 3 + 2];
    const float r0 = fx - xi, r1 = fy - yi, r2 = fz - zi;
    __syncthreads();
    float h = b1c;
#pragma unroll 8
    for (int f = 0; f < 128; ++f) h = fmaf(xj[f], w1[f * 256 + c], h);
    h = fmaf(r0, w1[128 * 256 + c], h);
    h = fmaf(r1, w1[129 * 256 + c], h);
    h = fmaf(r2, w1[130 * 256 + c], h);
    h = fmaxf(fmaf(h, scale, shift), 0.0f);
    hbuf[c] = h;
    __syncthreads();
    float o0 = b2c0, o1 = b2c1;
#pragma unroll 8
    for (int k2 = 0; k2 < 256; ++k2) {
      float hk = hbuf[k2];
      o0 = fmaf(hk, w2[k2 * 512 + c], o0);
      o1 = fmaf(hk, w2[k2 * 512 + c + 256], o1);
    }
    acc0 = fmaxf(acc0, fmaxf(o0, 0.0f));
    acc1 = fmaxf(acc1, fmaxf(o1, 0.0f));
    __syncthreads();
  }
  float* ob = out + ((size_t)(b * 512 + i)) * 512;
  ob[c] = acc0;
  ob[c + 256] = acc1;
  if (c == 0) bout[b * 512 + i] = (float)b;  // batch ids as f32
}

extern "C" void kernel_launch(void* const* d_in, const int* in_sizes, int n_in,
                              void* d_out, int out_size, void* d_ws, size_t ws_size,
                              hipStream_t stream) {
  const float* pos    = (const float*)d_in[0];
  const float* c1_w1  = (const float*)d_in[1];
  const float* c1_b1  = (const float*)d_in[2];
  const float* c1_g   = (const float*)d_in[3];
  const float* c1_be  = (const float*)d_in[4];
  const float* c1_m   = (const float*)d_in[5];
  const float* c1_v   = (const float*)d_in[6];
  const float* c1_w2  = (const float*)d_in[7];
  const float* c1_b2  = (const float*)d_in[8];
  const float* c2_w1  = (const float*)d_in[9];
  const float* c2_b1  = (const float*)d_in[10];
  const float* c2_g   = (const float*)d_in[11];
  const float* c2_be  = (const float*)d_in[12];
  const float* c2_m   = (const float*)d_in[13];
  const float* c2_v   = (const float*)d_in[14];
  const float* c2_w2  = (const float*)d_in[15];
  const float* c2_b2  = (const float*)d_in[16];

  char* ws = (char*)d_ws;
  float* pos1 = (float*)(ws + 0);        // 8*1024*3*4 =  98304
  int*   idx2 = (int*)  (ws + 98304);    // 8*512*4    =  16384
  float* pos2 = (float*)(ws + 114688);   // 8*512*3*4  =  49152
  float* x1   = (float*)(ws + 163840);   // 8*1024*128*4 = 4194304 (end 4358144)
  float* out  = (float*)d_out;

  fused_fps_kernel<<<8, 256, 0, stream>>>(pos, pos1, pos2, idx2);
  conv1_kernel<<<8 * 1024, 128, 0, stream>>>(pos1, c1_w1, c1_b1, c1_g, c1_be,
                                             c1_m, c1_v, c1_w2, c1_b2, x1);
  conv2_kernel<<<4096, 256, 0, stream>>>(pos2, idx2, x1, c2_w1, c2_b1, c2_g,
                                         c2_be, c2_m, c2_v, c2_w2, c2_b2, out,
                                         out + 2097152);
}

// Round 4
// 830.090 us; speedup vs baseline: 2.1168x; 1.8704x over previous
//
#include <hip/hip_runtime.h>

#define B_ 8
#define N_ 2048

#define REP8(M) M(0) M(1) M(2) M(3) M(4) M(5) M(6) M(7)

// one DPP max step: lanes without a source contribute -1.0f (identity; dists >= 0)
template <int CTRL>
__device__ __forceinline__ float dppMaxStep(float v) {
  int o = __builtin_amdgcn_update_dpp(__float_as_int(-1.0f), __float_as_int(v),
                                      CTRL, 0xF, 0xF, false);
  return fmaxf(v, __int_as_float(o));
}

__device__ __forceinline__ float waveMax(float v) {
  v = dppMaxStep<0x111>(v);  // row_shr:1
  v = dppMaxStep<0x112>(v);  // row_shr:2
  v = dppMaxStep<0x114>(v);  // row_shr:4
  v = dppMaxStep<0x118>(v);  // row_shr:8
  v = dppMaxStep<0x142>(v);  // row_bcast:15
  v = dppMaxStep<0x143>(v);  // row_bcast:31  -> lane 63 holds wave max
  return v;
}

// ---------------- fused normalize (f64 stats, fp32 ops match np) + FPS 2048->1024 ----------------
// One block per cloud, 256 threads (4 waves), 8 points/thread in explicit scalars.
__global__ __launch_bounds__(256) void norm_fps1_kernel(const float* __restrict__ pos,
                                                        float* __restrict__ pos1) {
  __shared__ float4 Sp[2048];     // normalized points (padded) for winner lookup
  __shared__ float2 red[2][4];    // double-buffered per-wave (max, idx) slots
  __shared__ double wsum[3][4];
  __shared__ float bc[6];
  const int b = blockIdx.x, tid = threadIdx.x;
  const float* base = pos + (size_t)b * N_ * 3;
  float px[8], py[8], pz[8];
  double sx = 0.0, sy = 0.0, sz = 0.0;
#pragma unroll
  for (int k = 0; k < 8; ++k) {
    int g = tid * 8 + k;
    px[k] = base[g * 3 + 0];
    py[k] = base[g * 3 + 1];
    pz[k] = base[g * 3 + 2];
    sx += (double)px[k]; sy += (double)py[k]; sz += (double)pz[k];
  }
  const int wid = tid >> 6, lid = tid & 63;
#pragma unroll
  for (int off = 32; off >= 1; off >>= 1) {
    sx += __shfl_down(sx, off);
    sy += __shfl_down(sy, off);
    sz += __shfl_down(sz, off);
  }
  if (lid == 0) { wsum[0][wid] = sx; wsum[1][wid] = sy; wsum[2][wid] = sz; }
  __syncthreads();
  if (tid == 0) {
    bc[0] = (float)((wsum[0][0] + wsum[0][1] + wsum[0][2] + wsum[0][3]) / 2048.0);
    bc[1] = (float)((wsum[1][0] + wsum[1][1] + wsum[1][2] + wsum[1][3]) / 2048.0);
    bc[2] = (float)((wsum[2][0] + wsum[2][1] + wsum[2][2] + wsum[2][3]) / 2048.0);
  }
  __syncthreads();
  const float mx = bc[0], my = bc[1], mz = bc[2];
  float dx[8], dy[8], dz[8];
  double qxs = 0.0, qys = 0.0, qzs = 0.0;
#pragma unroll
  for (int k = 0; k < 8; ++k) {
    dx[k] = __fsub_rn(px[k], mx);
    dy[k] = __fsub_rn(py[k], my);
    dz[k] = __fsub_rn(pz[k], mz);
    qxs += (double)__fmul_rn(dx[k], dx[k]);
    qys += (double)__fmul_rn(dy[k], dy[k]);
    qzs += (double)__fmul_rn(dz[k], dz[k]);
  }
#pragma unroll
  for (int off = 32; off >= 1; off >>= 1) {
    qxs += __shfl_down(qxs, off);
    qys += __shfl_down(qys, off);
    qzs += __shfl_down(qzs, off);
  }
  if (lid == 0) { wsum[0][wid] = qxs; wsum[1][wid] = qys; wsum[2][wid] = qzs; }
  __syncthreads();
  if (tid == 0) {
    bc[3] = __fadd_rn(__fsqrt_rn((float)((wsum[0][0]+wsum[0][1]+wsum[0][2]+wsum[0][3]) / 2047.0)), 1e-6f);
    bc[4] = __fadd_rn(__fsqrt_rn((float)((wsum[1][0]+wsum[1][1]+wsum[1][2]+wsum[1][3]) / 2047.0)), 1e-6f);
    bc[5] = __fadd_rn(__fsqrt_rn((float)((wsum[2][0]+wsum[2][1]+wsum[2][2]+wsum[2][3]) / 2047.0)), 1e-6f);
  }
  __syncthreads();
  const float isx = bc[3], isy = bc[4], isz = bc[5];
  // ---- explicit scalar FPS state: no arrays in the hot loop, cannot spill-by-SROA-failure ----
#define DECL8(i) float X##i, Y##i, Z##i, D##i;
  REP8(DECL8)
#define INIT8(i)                                                             \
  {                                                                          \
    X##i = __fdiv_rn(dx[i], isx);                                            \
    Y##i = __fdiv_rn(dy[i], isy);                                            \
    Z##i = __fdiv_rn(dz[i], isz);                                            \
    D##i = 1e10f;                                                            \
    Sp[tid * 8 + i] = make_float4(X##i, Y##i, Z##i, 0.0f);                   \
  }
  REP8(INIT8)
  __syncthreads();
  float4 q0 = Sp[0];  // deterministic FPS start at index 0 (LDS broadcast)
  float qx = q0.x, qy = q0.y, qz = q0.z;
  float* p1b = pos1 + (size_t)b * 1024 * 3;
  if (tid == 0) { p1b[0] = qx; p1b[1] = qy; p1b[2] = qz; }
  const int gbase = tid * 8;
  for (int t = 1; t < 1024; ++t) {
    // distance update: bit-exact ((dx*dx+dy*dy)+dz*dz), fminf
#define UPD8(i)                                                              \
    {                                                                        \
      float ddx = __fsub_rn(X##i, qx);                                       \
      float ddy = __fsub_rn(Y##i, qy);                                       \
      float ddz = __fsub_rn(Z##i, qz);                                       \
      float d = __fadd_rn(__fadd_rn(__fmul_rn(ddx, ddx), __fmul_rn(ddy, ddy)),\
                          __fmul_rn(ddz, ddz));                              \
      D##i = fminf(D##i, d);                                                 \
    }
    REP8(UPD8)
    // in-lane argmax tree; strict > in ascending order keeps smallest index on tie
    float v01 = (D1 > D0) ? D1 : D0;  int g01 = (D1 > D0) ? gbase + 1 : gbase + 0;
    float v23 = (D3 > D2) ? D3 : D2;  int g23 = (D3 > D2) ? gbase + 3 : gbase + 2;
    float v45 = (D5 > D4) ? D5 : D4;  int g45 = (D5 > D4) ? gbase + 5 : gbase + 4;
    float v67 = (D7 > D6) ? D7 : D6;  int g67 = (D7 > D6) ? gbase + 7 : gbase + 6;
    float v03 = (v23 > v01) ? v23 : v01;  int g03 = (v23 > v01) ? g23 : g01;
    float v47 = (v67 > v45) ? v67 : v45;  int g47 = (v67 > v45) ? g67 : g45;
    float bv  = (v47 > v03) ? v47 : v03;  int bg  = (v47 > v03) ? g47 : g03;
    // wave max (value only), then locate owner: lowest lane with bv==vmax = smallest index
    float mv = waveMax(bv);
    float vmax = __int_as_float(__builtin_amdgcn_readlane(__float_as_int(mv), 63));
    unsigned long long msk = __ballot(bv == vmax);
    int owner = __builtin_ctzll(msk);
    int gw = __builtin_amdgcn_readlane(bg, owner);
    const int par = t & 1;
    if (lid == 0) red[par][wid] = make_float2(vmax, __int_as_float(gw));
    __syncthreads();
    float2 r0 = red[par][0], r1 = red[par][1], r2 = red[par][2], r3 = red[par][3];
    float fv = r0.x; int fg = __float_as_int(r0.y);
    if (r1.x > fv) { fv = r1.x; fg = __float_as_int(r1.y); }
    if (r2.x > fv) { fv = r2.x; fg = __float_as_int(r2.y); }
    if (r3.x > fv) { fv = r3.x; fg = __float_as_int(r3.y); }
    float4 pw = Sp[fg];  // uniform index -> LDS broadcast
    qx = pw.x; qy = pw.y; qz = pw.z;
    if (tid == 0) {
      float* pp = p1b + t * 3;
      pp[0] = qx; pp[1] = qy; pp[2] = qz;
    }
  }
}

// ---------------- mid: fps2 (blocks 0..7, starts first) + conv1 (blocks 8..8199) ----------------
__global__ __launch_bounds__(128) void mid_kernel(
    const float* __restrict__ pos1,
    const float* __restrict__ w1, const float* __restrict__ b1,
    const float* __restrict__ g, const float* __restrict__ beta,
    const float* __restrict__ m, const float* __restrict__ v,
    const float* __restrict__ w2, const float* __restrict__ b2,
    float* __restrict__ x1out,
    int* __restrict__ idx2, float* __restrict__ pos2) {
  __shared__ union MidU {
    struct { int nbr[64]; int cnt; float hbuf[128]; } c;
    struct { float4 Sp2[1024]; float2 red2[2][2]; } f;
  } u;
  if (blockIdx.x >= 8) {
    // ---- conv1: one block per target point, sparse neighbor scan ----
    const int bb = blockIdx.x - 8;
    const int b = bb >> 10;
    const int i = bb & 1023;
    const int c = threadIdx.x;
    const float* pb = pos1 + (size_t)b * 1024 * 3;
    const float xi = pb[i * 3 + 0], yi = pb[i * 3 + 1], zi = pb[i * 3 + 2];
    if (c == 0) u.c.cnt = 0;
    __syncthreads();
    const float rr = (float)(0.1 * 0.1);  // matches weak-typed r*r rounding
#pragma unroll
    for (int k = 0; k < 8; ++k) {
      int j = c + (k << 7);
      float ddx = __fsub_rn(xi, pb[j * 3 + 0]);
      float ddy = __fsub_rn(yi, pb[j * 3 + 1]);
      float ddz = __fsub_rn(zi, pb[j * 3 + 2]);
      float d2 = __fadd_rn(__fadd_rn(__fmul_rn(ddx, ddx), __fmul_rn(ddy, ddy)),
                           __fmul_rn(ddz, ddz));
      if (d2 <= rr) {
        int s = atomicAdd(&u.c.cnt, 1);
        if (s < 64) u.c.nbr[s] = j;
      }
    }
    __syncthreads();
    const int n = min(u.c.cnt, 64);
    const float scale = g[c] / sqrtf(v[c] + 1e-5f);
    const float shift = beta[c] - m[c] * scale;
    float w1c[6];
#pragma unroll
    for (int f = 0; f < 6; ++f) w1c[f] = w1[f * 128 + c];
    const float b1c = b1[c], b2c = b2[c];
    float acc = 0.0f;  // relu >= 0 and self always valid
    for (int qq = 0; qq < n; ++qq) {
      const int j = u.c.nbr[qq];
      const float fx = pb[j * 3 + 0], fy = pb[j * 3 + 1], fz = pb[j * 3 + 2];
      float h = b1c;
      h = fmaf(fx, w1c[0], h);
      h = fmaf(fy, w1c[1], h);
      h = fmaf(fz, w1c[2], h);
      h = fmaf(fx - xi, w1c[3], h);
      h = fmaf(fy - yi, w1c[4], h);
      h = fmaf(fz - zi, w1c[5], h);
      h = fmaxf(fmaf(h, scale, shift), 0.0f);
      u.c.hbuf[c] = h;
      __syncthreads();
      float o = b2c;
#pragma unroll 8
      for (int k2 = 0; k2 < 128; ++k2) o = fmaf(u.c.hbuf[k2], w2[(k2 << 7) + c], o);
      acc = fmaxf(acc, fmaxf(o, 0.0f));
      __syncthreads();
    }
    x1out[((size_t)(b * 1024 + i)) * 128 + c] = acc;
  } else {
    // ---- fps2: 1024 -> 512, 128 threads (2 waves), 8 pts/thread in scalars ----
    const int b = blockIdx.x;
    const int tid = threadIdx.x;
    const int wid = tid >> 6, lid = tid & 63;
    const float* p1b = pos1 + (size_t)b * 1024 * 3;
#define DECLF(i) float X##i, Y##i, Z##i, D##i;
    REP8(DECLF)
#define LOADF(i)                                                             \
    {                                                                        \
      const float* pp = p1b + (tid * 8 + i) * 3;                             \
      X##i = pp[0]; Y##i = pp[1]; Z##i = pp[2];                              \
      D##i = 1e10f;                                                          \
      u.f.Sp2[tid * 8 + i] = make_float4(X##i, Y##i, Z##i, 0.0f);            \
    }
    REP8(LOADF)
    __syncthreads();
    float4 q0 = u.f.Sp2[0];
    float qx = q0.x, qy = q0.y, qz = q0.z;
    float* p2b = pos2 + (size_t)b * 512 * 3;
    int* i2b = idx2 + b * 512;
    if (tid == 0) {
      p2b[0] = qx; p2b[1] = qy; p2b[2] = qz;
      i2b[0] = 0;
    }
    const int gbase = tid * 8;
    for (int t = 1; t < 512; ++t) {
      REP8(UPD8)
      float v01 = (D1 > D0) ? D1 : D0;  int g01 = (D1 > D0) ? gbase + 1 : gbase + 0;
      float v23 = (D3 > D2) ? D3 : D2;  int g23 = (D3 > D2) ? gbase + 3 : gbase + 2;
      float v45 = (D5 > D4) ? D5 : D4;  int g45 = (D5 > D4) ? gbase + 5 : gbase + 4;
      float v67 = (D7 > D6) ? D7 : D6;  int g67 = (D7 > D6) ? gbase + 7 : gbase + 6;
      float v03 = (v23 > v01) ? v23 : v01;  int g03 = (v23 > v01) ? g23 : g01;
      float v47 = (v67 > v45) ? v67 : v45;  int g47 = (v67 > v45) ? g67 : g45;
      float bv  = (v47 > v03) ? v47 : v03;  int bg  = (v47 > v03) ? g47 : g03;
      float mv = waveMax(bv);
      float vmax = __int_as_float(__builtin_amdgcn_readlane(__float_as_int(mv), 63));
      unsigned long long msk = __ballot(bv == vmax);
      int owner = __builtin_ctzll(msk);
      int gw = __builtin_amdgcn_readlane(bg, owner);
      const int par = t & 1;
      if (lid == 0) u.f.red2[par][wid] = make_float2(vmax, __int_as_float(gw));
      __syncthreads();
      float2 r0 = u.f.red2[par][0], r1 = u.f.red2[par][1];
      float fv = r0.x; int fg = __float_as_int(r0.y);
      if (r1.x > fv) { fv = r1.x; fg = __float_as_int(r1.y); }
      float4 pw = u.f.Sp2[fg];
      qx = pw.x; qy = pw.y; qz = pw.z;
      if (tid == 0) {
        float* pp = p2b + t * 3;
        pp[0] = qx; pp[1] = qy; pp[2] = qz;
        i2b[t] = fg;
      }
    }
  }
}

// ---------------- level-2 ball conv (+ batch-id epilogue) ----------------
__global__ __launch_bounds__(256) void conv2_kernel(
    const float* __restrict__ pos2, const int* __restrict__ idx2,
    const float* __restrict__ x1,
    const float* __restrict__ w1, const float* __restrict__ b1,
    const float* __restrict__ g, const float* __restrict__ beta,
    const float* __restrict__ m, const float* __restrict__ v,
    const float* __restrict__ w2, const float* __restrict__ b2,
    float* __restrict__ out, float* __restrict__ bout) {
  const int b = blockIdx.x >> 9;
  const int i = blockIdx.x & 511;
  const int c = threadIdx.x;  // 0..255
  __shared__ int nbr[64];
  __shared__ int cnt;
  __shared__ float xj[128];
  __shared__ float hbuf[256];
  const float* pb = pos2 + (size_t)b * 512 * 3;
  const float xi = pb[i * 3 + 0], yi = pb[i * 3 + 1], zi = pb[i * 3 + 2];
  if (c == 0) cnt = 0;
  __syncthreads();
  const float rr = (float)(0.25 * 0.25);
#pragma unroll
  for (int k = 0; k < 2; ++k) {
    int j = c + (k << 8);
    float ddx = __fsub_rn(xi, pb[j * 3 + 0]);
    float ddy = __fsub_rn(yi, pb[j * 3 + 1]);
    float ddz = __fsub_rn(zi, pb[j * 3 + 2]);
    float d2 = __fadd_rn(__fadd_rn(__fmul_rn(ddx, ddx), __fmul_rn(ddy, ddy)),
                         __fmul_rn(ddz, ddz));
    if (d2 <= rr) {
      int s = atomicAdd(&cnt, 1);
      if (s < 64) nbr[s] = j;
    }
  }
  __syncthreads();
  const int n = min(cnt, 64);
  const float scale = g[c] / sqrtf(v[c] + 1e-5f);
  const float shift = beta[c] - m[c] * scale;
  const float b1c = b1[c];
  const float b2c0 = b2[c], b2c1 = b2[c + 256];
  float acc0 = 0.0f, acc1 = 0.0f;
  for (int q = 0; q < n; ++q) {
    const int j = nbr[q];
    const int src = idx2[b * 512 + j];
    if (c < 128) xj[c] = x1[((size_t)b * 1024 + src) * 128 + c];
    const float fx = pb[j * 3 + 0], fy = pb[j * 3 + 1], fz = pb[j * 3 + 2];
    const float r0 = fx - xi, r1 = fy - yi, r2 = fz - zi;
    __syncthreads();
    float h = b1c;
#pragma unroll 8
    for (int f = 0; f < 128; ++f) h = fmaf(xj[f], w1[f * 256 + c], h);
    h = fmaf(r0, w1[128 * 256 + c], h);
    h = fmaf(r1, w1[129 * 256 + c], h);
    h = fmaf(r2, w1[130 * 256 + c], h);
    h = fmaxf(fmaf(h, scale, shift), 0.0f);
    hbuf[c] = h;
    __syncthreads();
    float o0 = b2c0, o1 = b2c1;
#pragma unroll 8
    for (int k2 = 0; k2 < 256; ++k2) {
      float hk = hbuf[k2];
      o0 = fmaf(hk, w2[k2 * 512 + c], o0);
      o1 = fmaf(hk, w2[k2 * 512 + c + 256], o1);
    }
    acc0 = fmaxf(acc0, fmaxf(o0, 0.0f));
    acc1 = fmaxf(acc1, fmaxf(o1, 0.0f));
    __syncthreads();
  }
  float* ob = out + ((size_t)(b * 512 + i)) * 512;
  ob[c] = acc0;
  ob[c + 256] = acc1;
  if (c == 0) bout[b * 512 + i] = (float)b;  // batch ids as f32
}

extern "C" void kernel_launch(void* const* d_in, const int* in_sizes, int n_in,
                              void* d_out, int out_size, void* d_ws, size_t ws_size,
                              hipStream_t stream) {
  const float* pos    = (const float*)d_in[0];
  const float* c1_w1  = (const float*)d_in[1];
  const float* c1_b1  = (const float*)d_in[2];
  const float* c1_g   = (const float*)d_in[3];
  const float* c1_be  = (const float*)d_in[4];
  const float* c1_m   = (const float*)d_in[5];
  const float* c1_v   = (const float*)d_in[6];
  const float* c1_w2  = (const float*)d_in[7];
  const float* c1_b2  = (const float*)d_in[8];
  const float* c2_w1  = (const float*)d_in[9];
  const float* c2_b1  = (const float*)d_in[10];
  const float* c2_g   = (const float*)d_in[11];
  const float* c2_be  = (const float*)d_in[12];
  const float* c2_m   = (const float*)d_in[13];
  const float* c2_v   = (const float*)d_in[14];
  const float* c2_w2  = (const float*)d_in[15];
  const float* c2_b2  = (const float*)d_in[16];

  char* ws = (char*)d_ws;
  float* pos1 = (float*)(ws + 0);        // 8*1024*3*4 =  98304
  int*   idx2 = (int*)  (ws + 98304);    // 8*512*4    =  16384
  float* pos2 = (float*)(ws + 114688);   // 8*512*3*4  =  49152
  float* x1   = (float*)(ws + 163840);   // 8*1024*128*4 = 4194304 (end 4358144)
  float* out  = (float*)d_out;

  norm_fps1_kernel<<<8, 256, 0, stream>>>(pos, pos1);
  mid_kernel<<<8 + 8192, 128, 0, stream>>>(pos1, c1_w1, c1_b1, c1_g, c1_be,
                                           c1_m, c1_v, c1_w2, c1_b2, x1, idx2, pos2);
  conv2_kernel<<<4096, 256, 0, stream>>>(pos2, idx2, x1, c2_w1, c2_b1, c2_g,
                                         c2_be, c2_m, c2_v, c2_w2, c2_b2, out,
                                         out + 2097152);
}